// Round 5
// baseline (1638.060 us; speedup 1.0000x reference)
//
#include <hip/hip_runtime.h>
#include <hip/hip_bf16.h>
#include <cstdint>

#define HDIM 256
#define H2   128
#define NSLICE 16
#define SCOL   16    // columns per slice

using f32x4  = __attribute__((ext_vector_type(4))) float;
using bf16x8 = __attribute__((ext_vector_type(8))) short;    // 8 bf16 in 4 VGPRs
using u16x8  = __attribute__((ext_vector_type(8))) unsigned short;

__device__ inline unsigned short f2bf(float f) {             // round-to-nearest-even
    unsigned x = __builtin_bit_cast(unsigned, f);
    return (unsigned short)((x + 0x7fffu + ((x >> 16) & 1u)) >> 16);
}
__device__ inline float bf2f(unsigned short u) {
    unsigned x = ((unsigned)u) << 16;
    return __builtin_bit_cast(float, x);
}

// ---------------------------------------------------------------------------
__global__ void k_init(int* __restrict__ deg, int* __restrict__ cursor,
                       float* __restrict__ pooled, int n, int bh) {
    int i = blockIdx.x * blockDim.x + threadIdx.x;
    if (i < n) { deg[i] = 1; cursor[i] = 0; }
    if (i < bh) pooled[i] = 0.f;
}

__global__ void k_deg(const int* __restrict__ col, int* __restrict__ deg, int e) {
    int i = blockIdx.x * blockDim.x + threadIdx.x;
    if (i < e) atomicAdd(&deg[col[i]], 1);
}

__global__ void k_scan1(const int* __restrict__ deg, int* __restrict__ ptr,
                        int* __restrict__ bsum, int n) {
    __shared__ int sd[256];
    int i = blockIdx.x * 256 + threadIdx.x;
    int v = (i < n) ? (deg[i] - 1) : 0;
    sd[threadIdx.x] = v;
    __syncthreads();
    for (int off = 1; off < 256; off <<= 1) {
        int t = (threadIdx.x >= off) ? sd[threadIdx.x - off] : 0;
        __syncthreads();
        sd[threadIdx.x] += t;
        __syncthreads();
    }
    if (i < n) ptr[i] = sd[threadIdx.x] - v;
    if (threadIdx.x == 255) bsum[blockIdx.x] = sd[255];
}

__global__ void k_scan2(int* __restrict__ bsum, int nb) {
    __shared__ int sd[512];
    int t = threadIdx.x;
    int v = (t < nb) ? bsum[t] : 0;
    sd[t] = v;
    __syncthreads();
    for (int off = 1; off < 512; off <<= 1) {
        int x = (t >= off) ? sd[t - off] : 0;
        __syncthreads();
        sd[t] += x;
        __syncthreads();
    }
    if (t < nb) bsum[t] = sd[t] - v;
}

__global__ void k_scan3(int* __restrict__ ptr, const int* __restrict__ bsum, int n) {
    int i = blockIdx.x * 256 + threadIdx.x;
    if (i < n) ptr[i] += bsum[blockIdx.x];
}

__global__ void k_fill(const int* __restrict__ row, const int* __restrict__ col,
                       const int* __restrict__ ptr, int* __restrict__ cursor,
                       int* __restrict__ csr_src, int e) {
    int i = blockIdx.x * blockDim.x + threadIdx.x;
    if (i < e) {
        int v = col[i];
        int s = atomicAdd(&cursor[v], 1);
        csr_src[ptr[v] + s] = row[i];
    }
}

__global__ void k_dis(const int* __restrict__ deg, float* __restrict__ dis, int n) {
    int i = blockIdx.x * blockDim.x + threadIdx.x;
    if (i < n) dis[i] = rsqrtf((float)deg[i]);
}

__global__ void k_counts(const int* __restrict__ batch, float* __restrict__ counts,
                         int n, int B) {
    int g = blockIdx.x * blockDim.x + threadIdx.x;
    if (g >= B) return;
    auto lb = [&](int key) {
        int lo = 0, hi = n;
        while (lo < hi) { int mid = (lo + hi) >> 1; if (batch[mid] < key) lo = mid + 1; else hi = mid; }
        return lo;
    };
    counts[g] = (float)(lb(g + 1) - lb(g));
}

// AtomEncoder: wave per node, lane = 4 cols (float4 in, bf16x4 out); row-major out
__global__ __launch_bounds__(256) void k_atom(const int* __restrict__ x,
                                              const float* __restrict__ emb,
                                              short* __restrict__ h,
                                              int n, int F, int V) {
    int node = blockIdx.x * 4 + (threadIdx.x >> 6);
    int lane = threadIdx.x & 63;
    if (node >= n) return;
    int xv = x[node * F + (lane < F ? lane : 0)];
    float4 acc = {0.f, 0.f, 0.f, 0.f};
    for (int f = 0; f < F; ++f) {
        int idx = __shfl(xv, f, 64);
        const float4 v = *(const float4*)(emb + ((size_t)f * V + idx) * HDIM + lane * 4);
        acc.x += v.x; acc.y += v.y; acc.z += v.z; acc.w += v.w;
    }
    ushort4 o = { f2bf(acc.x), f2bf(acc.y), f2bf(acc.z), f2bf(acc.w) };
    *(ushort4*)(h + (size_t)node * HDIM + lane * 4) = o;
}

// transpose + convert W (fp32 [K][N]) -> Wt (bf16 [N][K])
__global__ void k_wt(const float* __restrict__ W, short* __restrict__ Wt) {
    int i = blockIdx.x * 256 + threadIdx.x;
    int nn = i >> 8, k = i & 255;
    Wt[nn * HDIM + k] = (short)f2bf(W[k * HDIM + nn]);
}

// bf16 MFMA GEMM: C = A[n,256] @ W; Wt = W^T bf16. Output COLUMN-SLICED:
// mS[slice][node][16], slice = col>>4. Tile 128x128 (2x2 waves of 64x64).
__global__ __launch_bounds__(256) void k_gemm(const short* __restrict__ A,
                                              const short* __restrict__ Wt,
                                              short* __restrict__ Co, int n) {
    int wid  = threadIdx.x >> 6;
    int lane = threadIdx.x & 63;
    int wr = wid >> 1, wc = wid & 1;
    int row0 = blockIdx.x * 128 + wr * 64;
    int col0 = blockIdx.y * 128 + wc * 64;
    int lm = lane & 15;
    int kg = lane >> 4;
    f32x4 acc[4][4] = {};
    for (int kk = 0; kk < HDIM; kk += 32) {
        bf16x8 a[4], b[4];
#pragma unroll
        for (int i = 0; i < 4; ++i) {
            int r = row0 + i * 16 + lm;
            a[i] = (r < n) ? *(const bf16x8*)(A + (size_t)r * HDIM + kk + kg * 8)
                           : (bf16x8)(short)0;
        }
#pragma unroll
        for (int j = 0; j < 4; ++j) {
            int c = col0 + j * 16 + lm;
            b[j] = *(const bf16x8*)(Wt + (size_t)c * HDIM + kk + kg * 8);
        }
#pragma unroll
        for (int i = 0; i < 4; ++i)
#pragma unroll
            for (int j = 0; j < 4; ++j)
                acc[i][j] = __builtin_amdgcn_mfma_f32_16x16x32_bf16(a[i], b[j], acc[i][j], 0, 0, 0);
    }
#pragma unroll
    for (int i = 0; i < 4; ++i)
#pragma unroll
        for (int j = 0; j < 4; ++j) {
            int cbase = col0 + j * 16;                       // multiple of 16
            short* slab = Co + (size_t)(cbase >> 4) * n * SCOL;
#pragma unroll
            for (int r4 = 0; r4 < 4; ++r4) {
                int r = row0 + i * 16 + kg * 4 + r4;
                if (r < n) slab[(size_t)r * SCOL + lm] = (short)f2bf(acc[i][j][r4]);
            }
        }
}

// gather-aggregate over column-sliced messages, R4-style instruction economy.
// block b: phase ph=b/(8G); slice=(q&7)|(ph<<3) -> slab (3.2MB) pinned per XCD,
// L2-resident. Wave = 2 nodes (halves); edge i of a node handled by 2 lanes
// (parity) loading ushort8 (16B) from the slab; 16 edges in flight per node.
// Butterfly shfl_xor reduce (offsets 2..16) preserves (half,parity).
__global__ __launch_bounds__(256) void k_agg(const short* __restrict__ mS,
                                             const int* __restrict__ csr_src,
                                             const int* __restrict__ ptr,
                                             const int* __restrict__ deg,
                                             const float* __restrict__ dis,
                                             const float* __restrict__ bias,
                                             short* __restrict__ xout,
                                             int n, int G) {
    int b = blockIdx.x;
    int p8G = 8 * G;
    int ph = b / p8G;
    int q = b - ph * p8G;
    int slice = (q & 7) | (ph << 3);
    int group = q >> 3;
    int wv   = threadIdx.x >> 6;
    int lane = threadIdx.x & 63;
    int h  = lane >> 5;          // which node of the pair
    int il = lane & 31;
    int par = il & 1;            // 8-col parity group
    int node = group * 8 + wv * 2 + h;
    bool alive = node < n;
    const unsigned short* slab = (const unsigned short*)mS + (size_t)slice * n * SCOL;
    float dv  = alive ? dis[node] : 0.f;
    int start = alive ? ptr[node] : 0;
    int cnt   = alive ? (deg[node] - 1) : 0;
    int maxc  = max(cnt, __shfl_xor(cnt, 32, 64));
    float acc[8] = {};
    int uu = 0; float du = 0.f;
    int iters = (maxc + 15) >> 4;
    for (int it = 0; it < iters; ++it) {
        if ((it & 1) == 0) {                 // prefetch 32 indices per node
            int idx = (it >> 1) * 32 + il;
            if (idx < cnt) {
                uu = __builtin_nontemporal_load(&csr_src[start + idx]);
                du = dis[uu];
            } else { uu = 0; du = 0.f; }
        }
        int src = (h << 5) + ((it & 1) << 4) + (il >> 1);
        int u   = __shfl(uu, src, 64);
        float w = dv * __shfl(du, src, 64);
        if (it * 16 + (il >> 1) >= cnt) { u = 0; w = 0.f; }
        u16x8 r = *(const u16x8*)(slab + (size_t)u * SCOL + par * 8);
#pragma unroll
        for (int j = 0; j < 8; ++j) acc[j] += w * bf2f(r[j]);
    }
#pragma unroll
    for (int off = 2; off <= 16; off <<= 1)
#pragma unroll
        for (int j = 0; j < 8; ++j) acc[j] += __shfl_xor(acc[j], off, 64);
    if (alive && il < 2) {                   // lanes (h,par) = il<2 hold totals
        u16x8 s = *(const u16x8*)(slab + (size_t)node * SCOL + par * 8);
        float sw = dv * dv;
        const float4 b0 = *(const float4*)(bias + slice * SCOL + par * 8);
        const float4 b1 = *(const float4*)(bias + slice * SCOL + par * 8 + 4);
        float bb[8] = {b0.x, b0.y, b0.z, b0.w, b1.x, b1.y, b1.z, b1.w};
        u16x8 o;
#pragma unroll
        for (int j = 0; j < 8; ++j) {
            float v = acc[j] + sw * bf2f(s[j]) + bb[j];
            o[j] = f2bf(fmaxf(v, 0.f));
        }
        __builtin_nontemporal_store(o,
            (u16x8*)((unsigned short*)xout + (size_t)node * HDIM + slice * SCOL + par * 8));
    }
}

// pooling: sum x1+x2+x3 rows per graph (sorted batch -> contiguous ranges)
__global__ __launch_bounds__(256) void k_pool(const short* __restrict__ x1,
                                              const short* __restrict__ x2,
                                              const short* __restrict__ x3,
                                              const int* __restrict__ batch,
                                              float* __restrict__ pooled, int n) {
    int g = blockIdx.x, seg = blockIdx.y, t = threadIdx.x;
    auto lb = [&](int key) {
        int lo = 0, hi = n;
        while (lo < hi) { int mid = (lo + hi) >> 1; if (batch[mid] < key) lo = mid + 1; else hi = mid; }
        return lo;
    };
    int lo = lb(g), hi = lb(g + 1);
    int len = hi - lo;
    int per = (len + (int)gridDim.y - 1) / (int)gridDim.y;
    int s0 = lo + seg * per;
    int s1 = s0 + per; if (s1 > hi) s1 = hi;
    float acc = 0.f;
    for (int r = s0; r < s1; ++r) {
        size_t base = (size_t)r * HDIM + t;
        acc += bf2f((unsigned short)x1[base]) + bf2f((unsigned short)x2[base])
             + bf2f((unsigned short)x3[base]);
    }
    if (s0 < s1) atomicAdd(&pooled[g * HDIM + t], acc);
}

// classifier: mean-pool finalize + 2-layer MLP; block per graph
__global__ __launch_bounds__(H2) void k_cls(const float* __restrict__ pooled,
                                            const float* __restrict__ counts,
                                            const float* __restrict__ cw1,
                                            const float* __restrict__ cb1,
                                            const float* __restrict__ cw2,
                                            const float* __restrict__ cb2,
                                            float* __restrict__ out, int B, int C) {
    __shared__ float sp[HDIM];
    __shared__ float sh[H2];
    int g = blockIdx.x, t = threadIdx.x;
    float inv = 1.0f / counts[g];
    sp[t] = pooled[g * HDIM + t] * inv;
    sp[t + H2] = pooled[g * HDIM + t + H2] * inv;
    __syncthreads();
    float acc = cb1[t];
    for (int h = 0; h < HDIM; ++h) acc += sp[h] * cw1[h * H2 + t];
    sh[t] = fmaxf(acc, 0.f);
    __syncthreads();
    if (t < C) {
        float o = cb2[t];
        for (int j = 0; j < H2; ++j) o += sh[j] * cw2[j * C + t];
        out[g * C + t] = o;
    }
    if (g == 0 && t == 0) out[B * C] = 0.f;
}

// ---------------------------------------------------------------------------
extern "C" void kernel_launch(void* const* d_in, const int* in_sizes, int n_in,
                              void* d_out, int out_size, void* d_ws, size_t ws_size,
                              hipStream_t stream) {
    const int* x      = (const int*)d_in[0];
    const int* erow   = (const int*)d_in[1];
    const int* batch  = (const int*)d_in[2];
    const float* emb  = (const float*)d_in[3];
    const float* W1   = (const float*)d_in[4];
    const float* b1   = (const float*)d_in[5];
    const float* W2   = (const float*)d_in[6];
    const float* b2   = (const float*)d_in[7];
    const float* W3   = (const float*)d_in[8];
    const float* b3   = (const float*)d_in[9];
    const float* cw1  = (const float*)d_in[10];
    const float* cb1  = (const float*)d_in[11];
    const float* cw2  = (const float*)d_in[12];
    const float* cb2  = (const float*)d_in[13];
    float* out = (float*)d_out;

    const int N = in_sizes[2];
    const int E = in_sizes[1] / 2;
    const int F = in_sizes[0] / N;
    const int V = in_sizes[3] / (F * HDIM);
    const int C = in_sizes[13];
    const int B = (out_size - 1) / C;
    const int* ecol = erow + E;

    char* w = (char*)d_ws;
    auto carve = [&](size_t bytes) {
        void* p = (void*)w;
        w += (bytes + 255) & ~(size_t)255;
        return p;
    };
    short* P0     = (short*)carve((size_t)N * HDIM * 2);   // h0, later x3
    short* P1     = (short*)carve((size_t)N * HDIM * 2);   // x1
    short* P2     = (short*)carve((size_t)N * HDIM * 2);   // x2
    short* mS     = (short*)carve((size_t)N * HDIM * 2);   // sliced GEMM output
    short* Wt1    = (short*)carve((size_t)HDIM * HDIM * 2);
    short* Wt2    = (short*)carve((size_t)HDIM * HDIM * 2);
    short* Wt3    = (short*)carve((size_t)HDIM * HDIM * 2);
    float* dis    = (float*)carve((size_t)N * 4);
    float* pooled = (float*)carve((size_t)B * HDIM * 4);
    float* counts = (float*)carve((size_t)B * 4);
    int* deg      = (int*)carve((size_t)N * 4);
    int* ptr      = (int*)carve((size_t)N * 4);
    int* cursor   = (int*)carve((size_t)N * 4);
    int* bsum     = (int*)carve(1024 * 4);
    int* csr      = (int*)carve((size_t)E * 4);

    int nblk = (N + 255) / 256;
    int initspan = (B * HDIM > N) ? B * HDIM : N;

    k_init<<<(initspan + 255) / 256, 256, 0, stream>>>(deg, cursor, pooled, N, B * HDIM);
    k_deg<<<(E + 255) / 256, 256, 0, stream>>>(ecol, deg, E);
    k_scan1<<<nblk, 256, 0, stream>>>(deg, ptr, bsum, N);
    k_scan2<<<1, 512, 0, stream>>>(bsum, nblk);
    k_scan3<<<nblk, 256, 0, stream>>>(ptr, bsum, N);
    k_fill<<<(E + 255) / 256, 256, 0, stream>>>(erow, ecol, ptr, cursor, csr, E);
    k_dis<<<nblk, 256, 0, stream>>>(deg, dis, N);
    k_counts<<<(B + 255) / 256, 256, 0, stream>>>(batch, counts, N, B);
    k_wt<<<HDIM, 256, 0, stream>>>(W1, Wt1);
    k_wt<<<HDIM, 256, 0, stream>>>(W2, Wt2);
    k_wt<<<HDIM, 256, 0, stream>>>(W3, Wt3);
    k_atom<<<(N + 3) / 4, 256, 0, stream>>>(x, emb, P0, N, F, V);

    dim3 ggrid((N + 127) / 128, 2);
    const int G = (N + 7) / 8;            // node-groups per slice (8 nodes/block)
    const int agrid = NSLICE * G;

    k_gemm<<<ggrid, 256, 0, stream>>>(P0, Wt1, mS, N);
    k_agg<<<agrid, 256, 0, stream>>>(mS, csr, ptr, deg, dis, b1, P1, N, G);
    k_gemm<<<ggrid, 256, 0, stream>>>(P1, Wt2, mS, N);
    k_agg<<<agrid, 256, 0, stream>>>(mS, csr, ptr, deg, dis, b2, P2, N, G);
    k_gemm<<<ggrid, 256, 0, stream>>>(P2, Wt3, mS, N);
    k_agg<<<agrid, 256, 0, stream>>>(mS, csr, ptr, deg, dis, b3, P0, N, G);

    dim3 pgrid(B, 4);
    k_pool<<<pgrid, 256, 0, stream>>>(P1, P2, P0, batch, pooled, N);
    k_cls<<<B, H2, 0, stream>>>(pooled, counts, cw1, cb1, cw2, cb2, out, B, C);
}

// Round 6
// 839.512 us; speedup vs baseline: 1.9512x; 1.9512x over previous
//
#include <hip/hip_runtime.h>
#include <hip/hip_bf16.h>
#include <cstdint>

#define HDIM 256
#define H2   128

using f32x4  = __attribute__((ext_vector_type(4))) float;
using bf16x8 = __attribute__((ext_vector_type(8))) short;    // 8 bf16 in 4 VGPRs
using u16x8  = __attribute__((ext_vector_type(8))) unsigned short;

__device__ inline unsigned short f2bf(float f) {             // round-to-nearest-even
    unsigned x = __builtin_bit_cast(unsigned, f);
    return (unsigned short)((x + 0x7fffu + ((x >> 16) & 1u)) >> 16);
}
__device__ inline float bf2f(unsigned short u) {
    unsigned x = ((unsigned)u) << 16;
    return __builtin_bit_cast(float, x);
}

// ---------------------------------------------------------------------------
__global__ void k_init(int* __restrict__ deg, int* __restrict__ cursor,
                       float* __restrict__ pooled, int n, int bh) {
    int i = blockIdx.x * blockDim.x + threadIdx.x;
    if (i < n) { deg[i] = 1; cursor[i] = 0; }
    if (i < bh) pooled[i] = 0.f;
}

__global__ void k_deg(const int* __restrict__ col, int* __restrict__ deg, int e) {
    int i = blockIdx.x * blockDim.x + threadIdx.x;
    if (i < e) atomicAdd(&deg[col[i]], 1);
}

__global__ void k_scan1(const int* __restrict__ deg, int* __restrict__ ptr,
                        int* __restrict__ bsum, int n) {
    __shared__ int sd[256];
    int i = blockIdx.x * 256 + threadIdx.x;
    int v = (i < n) ? (deg[i] - 1) : 0;
    sd[threadIdx.x] = v;
    __syncthreads();
    for (int off = 1; off < 256; off <<= 1) {
        int t = (threadIdx.x >= off) ? sd[threadIdx.x - off] : 0;
        __syncthreads();
        sd[threadIdx.x] += t;
        __syncthreads();
    }
    if (i < n) ptr[i] = sd[threadIdx.x] - v;
    if (threadIdx.x == 255) bsum[blockIdx.x] = sd[255];
}

__global__ void k_scan2(int* __restrict__ bsum, int nb) {
    __shared__ int sd[512];
    int t = threadIdx.x;
    int v = (t < nb) ? bsum[t] : 0;
    sd[t] = v;
    __syncthreads();
    for (int off = 1; off < 512; off <<= 1) {
        int x = (t >= off) ? sd[t - off] : 0;
        __syncthreads();
        sd[t] += x;
        __syncthreads();
    }
    if (t < nb) bsum[t] = sd[t] - v;
}

// scan finalize + dis = deg^-0.5 (fused)
__global__ void k_scan3(int* __restrict__ ptr, const int* __restrict__ bsum,
                        const int* __restrict__ deg, float* __restrict__ dis, int n) {
    int i = blockIdx.x * 256 + threadIdx.x;
    if (i < n) {
        ptr[i] += bsum[blockIdx.x];
        dis[i] = rsqrtf((float)deg[i]);
    }
}

__global__ void k_fill(const int* __restrict__ row, const int* __restrict__ col,
                       const int* __restrict__ ptr, int* __restrict__ cursor,
                       int* __restrict__ csr_src, int e) {
    int i = blockIdx.x * blockDim.x + threadIdx.x;
    if (i < e) {
        int v = col[i];
        int s = atomicAdd(&cursor[v], 1);
        csr_src[ptr[v] + s] = row[i];
    }
}

__global__ void k_counts(const int* __restrict__ batch, float* __restrict__ counts,
                         int n, int B) {
    int g = blockIdx.x * blockDim.x + threadIdx.x;
    if (g >= B) return;
    auto lb = [&](int key) {
        int lo = 0, hi = n;
        while (lo < hi) { int mid = (lo + hi) >> 1; if (batch[mid] < key) lo = mid + 1; else hi = mid; }
        return lo;
    };
    counts[g] = (float)(lb(g + 1) - lb(g));
}

// AtomEncoder: wave per node, lane = 4 cols (float4 in, bf16x4 out); row-major out
__global__ __launch_bounds__(256) void k_atom(const int* __restrict__ x,
                                              const float* __restrict__ emb,
                                              short* __restrict__ h,
                                              int n, int F, int V) {
    int node = blockIdx.x * 4 + (threadIdx.x >> 6);
    int lane = threadIdx.x & 63;
    if (node >= n) return;
    int xv = x[node * F + (lane < F ? lane : 0)];
    float4 acc = {0.f, 0.f, 0.f, 0.f};
    for (int f = 0; f < F; ++f) {
        int idx = __shfl(xv, f, 64);
        const float4 v = *(const float4*)(emb + ((size_t)f * V + idx) * HDIM + lane * 4);
        acc.x += v.x; acc.y += v.y; acc.z += v.z; acc.w += v.w;
    }
    ushort4 o = { f2bf(acc.x), f2bf(acc.y), f2bf(acc.z), f2bf(acc.w) };
    *(ushort4*)(h + (size_t)node * HDIM + lane * 4) = o;
}

// transpose + convert all three W (fp32 [K][N]) -> Wt (bf16 [N][K]); grid.y = layer
__global__ void k_wt3(const float* __restrict__ W1, const float* __restrict__ W2,
                      const float* __restrict__ W3, short* __restrict__ Wt1,
                      short* __restrict__ Wt2, short* __restrict__ Wt3) {
    const float* W = (blockIdx.y == 0) ? W1 : (blockIdx.y == 1) ? W2 : W3;
    short* Wt      = (blockIdx.y == 0) ? Wt1 : (blockIdx.y == 1) ? Wt2 : Wt3;
    int i = blockIdx.x * 256 + threadIdx.x;
    int nn = i >> 8, k = i & 255;
    Wt[nn * HDIM + k] = (short)f2bf(W[k * HDIM + nn]);
}

// bf16 MFMA GEMM: C[n,256] = A[n,256] @ W, Wt = W^T bf16.
// One block = 128 rows x ALL 256 cols (A-tile fetched once); 4 waves, each
// wave 64x128 (acc[4][8]). Frag layouts per m89: A row=lane&15,k=(lane>>4)*8+i;
// D col=lane&15,row=(lane>>4)*4+reg.
__global__ __launch_bounds__(256) void k_gemm(const short* __restrict__ A,
                                              const short* __restrict__ Wt,
                                              short* __restrict__ Co, int n) {
    int wid  = threadIdx.x >> 6;
    int lane = threadIdx.x & 63;
    int wr = wid >> 1, wc = wid & 1;
    int row0 = blockIdx.x * 128 + wr * 64;
    int col0 = wc * 128;
    int lm = lane & 15;
    int kg = lane >> 4;
    f32x4 acc[4][8] = {};
    for (int kk = 0; kk < HDIM; kk += 32) {
        bf16x8 a[4], b[8];
#pragma unroll
        for (int i = 0; i < 4; ++i) {
            int r = row0 + i * 16 + lm;
            a[i] = (r < n) ? *(const bf16x8*)(A + (size_t)r * HDIM + kk + kg * 8)
                           : (bf16x8)(short)0;
        }
#pragma unroll
        for (int j = 0; j < 8; ++j) {
            int c = col0 + j * 16 + lm;
            b[j] = *(const bf16x8*)(Wt + (size_t)c * HDIM + kk + kg * 8);
        }
#pragma unroll
        for (int i = 0; i < 4; ++i)
#pragma unroll
            for (int j = 0; j < 8; ++j)
                acc[i][j] = __builtin_amdgcn_mfma_f32_16x16x32_bf16(a[i], b[j], acc[i][j], 0, 0, 0);
    }
#pragma unroll
    for (int i = 0; i < 4; ++i)
#pragma unroll
        for (int j = 0; j < 8; ++j) {
            int c = col0 + j * 16 + lm;
#pragma unroll
            for (int r4 = 0; r4 < 4; ++r4) {
                int r = row0 + i * 16 + kg * 4 + r4;
                if (r < n) Co[(size_t)r * HDIM + c] = (short)f2bf(acc[i][j][r4]);
            }
        }
}

// gather-aggregate: wave per node (R4 structure), supersteps of 8 edges with
// 4 independent row loads in flight per lane (MLP-deep pipeline).
// 32 lanes x ushort8 = one 512B message row; halves split even/odd edges;
// final xor-32 reduce merges them.
__global__ __launch_bounds__(256) void k_agg(const short* __restrict__ mS,
                                             const int* __restrict__ csr_src,
                                             const int* __restrict__ ptr,
                                             const int* __restrict__ deg,
                                             const float* __restrict__ dis,
                                             const float* __restrict__ bias,
                                             short* __restrict__ xout, int n) {
    int node = blockIdx.x * 4 + (threadIdx.x >> 6);
    if (node >= n) return;
    int lane = threadIdx.x & 63;
    int half = lane >> 5;
    int cl = lane & 31;                       // col group: 8 cols
    const unsigned short* m = (const unsigned short*)mS;
    float dv = dis[node];
    float acc[8] = {};
    if (half == 0) {                          // self-loop term
        u16x8 r = *(const u16x8*)(m + (size_t)node * HDIM + cl * 8);
        float sw = dv * dv;
#pragma unroll
        for (int j = 0; j < 8; ++j) acc[j] = sw * bf2f(r[j]);
    }
    int start = ptr[node];
    int cnt = deg[node] - 1;
    for (int base = 0; base < cnt; base += 64) {
        int mm = cnt - base; if (mm > 64) mm = 64;
        int uu = 0; float du = 0.f;
        if (lane < mm) {
            uu = __builtin_nontemporal_load(&csr_src[start + base + lane]);
            du = dis[uu];
        }
        int nst = (mm + 7) >> 3;              // supersteps of 8 edges (4/half)
        for (int s = 0; s < nst; ++s) {
            u16x8 r[4]; float w[4];
#pragma unroll
            for (int q = 0; q < 4; ++q) {     // issue 4 independent loads
                int i = 8 * s + 2 * q + half;
                int u   = __shfl(uu, i & 63, 64);
                float ww = dv * __shfl(du, i & 63, 64);
                bool v = i < mm;
                w[q] = v ? ww : 0.f;
                r[q] = *(const u16x8*)(m + (size_t)(v ? u : 0) * HDIM + cl * 8);
            }
#pragma unroll
            for (int q = 0; q < 4; ++q)
#pragma unroll
                for (int j = 0; j < 8; ++j) acc[j] += w[q] * bf2f(r[q][j]);
        }
    }
#pragma unroll
    for (int j = 0; j < 8; ++j) acc[j] += __shfl_xor(acc[j], 32, 64);
    if (half == 0) {
        const float4 b0 = *(const float4*)(bias + cl * 8);
        const float4 b1 = *(const float4*)(bias + cl * 8 + 4);
        float bb[8] = {b0.x, b0.y, b0.z, b0.w, b1.x, b1.y, b1.z, b1.w};
        u16x8 o;
#pragma unroll
        for (int j = 0; j < 8; ++j)
            o[j] = f2bf(fmaxf(acc[j] + bb[j], 0.f));
        *(u16x8*)((unsigned short*)xout + (size_t)node * HDIM + cl * 8) = o;
    }
}

// pooling: sum x1+x2+x3 rows per graph (sorted batch -> contiguous ranges)
__global__ __launch_bounds__(256) void k_pool(const short* __restrict__ x1,
                                              const short* __restrict__ x2,
                                              const short* __restrict__ x3,
                                              const int* __restrict__ batch,
                                              float* __restrict__ pooled, int n) {
    int g = blockIdx.x, seg = blockIdx.y, t = threadIdx.x;
    auto lb = [&](int key) {
        int lo = 0, hi = n;
        while (lo < hi) { int mid = (lo + hi) >> 1; if (batch[mid] < key) lo = mid + 1; else hi = mid; }
        return lo;
    };
    int lo = lb(g), hi = lb(g + 1);
    int len = hi - lo;
    int per = (len + (int)gridDim.y - 1) / (int)gridDim.y;
    int s0 = lo + seg * per;
    int s1 = s0 + per; if (s1 > hi) s1 = hi;
    float acc = 0.f;
    for (int r = s0; r < s1; ++r) {
        size_t base = (size_t)r * HDIM + t;
        acc += bf2f((unsigned short)x1[base]) + bf2f((unsigned short)x2[base])
             + bf2f((unsigned short)x3[base]);
    }
    if (s0 < s1) atomicAdd(&pooled[g * HDIM + t], acc);
}

// classifier: mean-pool finalize + 2-layer MLP; block per graph
__global__ __launch_bounds__(H2) void k_cls(const float* __restrict__ pooled,
                                            const float* __restrict__ counts,
                                            const float* __restrict__ cw1,
                                            const float* __restrict__ cb1,
                                            const float* __restrict__ cw2,
                                            const float* __restrict__ cb2,
                                            float* __restrict__ out, int B, int C) {
    __shared__ float sp[HDIM];
    __shared__ float sh[H2];
    int g = blockIdx.x, t = threadIdx.x;
    float inv = 1.0f / counts[g];
    sp[t] = pooled[g * HDIM + t] * inv;
    sp[t + H2] = pooled[g * HDIM + t + H2] * inv;
    __syncthreads();
    float acc = cb1[t];
    for (int h = 0; h < HDIM; ++h) acc += sp[h] * cw1[h * H2 + t];
    sh[t] = fmaxf(acc, 0.f);
    __syncthreads();
    if (t < C) {
        float o = cb2[t];
        for (int j = 0; j < H2; ++j) o += sh[j] * cw2[j * C + t];
        out[g * C + t] = o;
    }
    if (g == 0 && t == 0) out[B * C] = 0.f;
}

// ---------------------------------------------------------------------------
extern "C" void kernel_launch(void* const* d_in, const int* in_sizes, int n_in,
                              void* d_out, int out_size, void* d_ws, size_t ws_size,
                              hipStream_t stream) {
    const int* x      = (const int*)d_in[0];
    const int* erow   = (const int*)d_in[1];
    const int* batch  = (const int*)d_in[2];
    const float* emb  = (const float*)d_in[3];
    const float* W1   = (const float*)d_in[4];
    const float* b1   = (const float*)d_in[5];
    const float* W2   = (const float*)d_in[6];
    const float* b2   = (const float*)d_in[7];
    const float* W3   = (const float*)d_in[8];
    const float* b3   = (const float*)d_in[9];
    const float* cw1  = (const float*)d_in[10];
    const float* cb1  = (const float*)d_in[11];
    const float* cw2  = (const float*)d_in[12];
    const float* cb2  = (const float*)d_in[13];
    float* out = (float*)d_out;

    const int N = in_sizes[2];
    const int E = in_sizes[1] / 2;
    const int F = in_sizes[0] / N;
    const int V = in_sizes[3] / (F * HDIM);
    const int C = in_sizes[13];
    const int B = (out_size - 1) / C;
    const int* ecol = erow + E;

    char* w = (char*)d_ws;
    auto carve = [&](size_t bytes) {
        void* p = (void*)w;
        w += (bytes + 255) & ~(size_t)255;
        return p;
    };
    short* P0     = (short*)carve((size_t)N * HDIM * 2);   // h0, later x3
    short* P1     = (short*)carve((size_t)N * HDIM * 2);   // x1
    short* P2     = (short*)carve((size_t)N * HDIM * 2);   // x2
    short* mS     = (short*)carve((size_t)N * HDIM * 2);   // GEMM output (messages)
    short* Wt1    = (short*)carve((size_t)HDIM * HDIM * 2);
    short* Wt2    = (short*)carve((size_t)HDIM * HDIM * 2);
    short* Wt3    = (short*)carve((size_t)HDIM * HDIM * 2);
    float* dis    = (float*)carve((size_t)N * 4);
    float* pooled = (float*)carve((size_t)B * HDIM * 4);
    float* counts = (float*)carve((size_t)B * 4);
    int* deg      = (int*)carve((size_t)N * 4);
    int* ptr      = (int*)carve((size_t)N * 4);
    int* cursor   = (int*)carve((size_t)N * 4);
    int* bsum     = (int*)carve(1024 * 4);
    int* csr      = (int*)carve((size_t)E * 4);

    int nblk = (N + 255) / 256;
    int initspan = (B * HDIM > N) ? B * HDIM : N;

    k_init<<<(initspan + 255) / 256, 256, 0, stream>>>(deg, cursor, pooled, N, B * HDIM);
    k_deg<<<(E + 255) / 256, 256, 0, stream>>>(ecol, deg, E);
    k_scan1<<<nblk, 256, 0, stream>>>(deg, ptr, bsum, N);
    k_scan2<<<1, 512, 0, stream>>>(bsum, nblk);
    k_scan3<<<nblk, 256, 0, stream>>>(ptr, bsum, deg, dis, N);
    k_fill<<<(E + 255) / 256, 256, 0, stream>>>(erow, ecol, ptr, cursor, csr, E);
    k_counts<<<(B + 255) / 256, 256, 0, stream>>>(batch, counts, N, B);
    dim3 wgrid(HDIM, 3);
    k_wt3<<<wgrid, 256, 0, stream>>>(W1, W2, W3, Wt1, Wt2, Wt3);
    k_atom<<<(N + 3) / 4, 256, 0, stream>>>(x, emb, P0, N, F, V);

    int ggrid = (N + 127) / 128;
    int agrid = (N + 3) / 4;

    k_gemm<<<ggrid, 256, 0, stream>>>(P0, Wt1, mS, N);
    k_agg<<<agrid, 256, 0, stream>>>(mS, csr, ptr, deg, dis, b1, P1, N);
    k_gemm<<<ggrid, 256, 0, stream>>>(P1, Wt2, mS, N);
    k_agg<<<agrid, 256, 0, stream>>>(mS, csr, ptr, deg, dis, b2, P2, N);
    k_gemm<<<ggrid, 256, 0, stream>>>(P2, Wt3, mS, N);
    k_agg<<<agrid, 256, 0, stream>>>(mS, csr, ptr, deg, dis, b3, P0, N);

    dim3 pgrid(B, 4);
    k_pool<<<pgrid, 256, 0, stream>>>(P1, P2, P0, batch, pooled, N);
    k_cls<<<B, H2, 0, stream>>>(pooled, counts, cw1, cb1, cw2, cb2, out, B, C);
}

// Round 7
// 837.254 us; speedup vs baseline: 1.9565x; 1.0027x over previous
//
#include <hip/hip_runtime.h>
#include <hip/hip_bf16.h>
#include <cstdint>

#define HDIM 256
#define H2   128

using f32x4  = __attribute__((ext_vector_type(4))) float;
using bf16x8 = __attribute__((ext_vector_type(8))) short;    // 8 bf16 in 4 VGPRs
using u16x8  = __attribute__((ext_vector_type(8))) unsigned short;

__device__ inline unsigned short f2bf(float f) {             // round-to-nearest-even
    unsigned x = __builtin_bit_cast(unsigned, f);
    return (unsigned short)((x + 0x7fffu + ((x >> 16) & 1u)) >> 16);
}
__device__ inline float bf2f(unsigned short u) {
    unsigned x = ((unsigned)u) << 16;
    return __builtin_bit_cast(float, x);
}

// ---------------------------------------------------------------------------
__global__ void k_init(int* __restrict__ deg, int* __restrict__ cursor,
                       float* __restrict__ pooled, int n, int bh) {
    int i = blockIdx.x * blockDim.x + threadIdx.x;
    if (i < n) { deg[i] = 1; cursor[i] = 0; }
    if (i < bh) pooled[i] = 0.f;
}

__global__ void k_deg(const int* __restrict__ col, int* __restrict__ deg, int e) {
    int i = blockIdx.x * blockDim.x + threadIdx.x;
    if (i < e) atomicAdd(&deg[col[i]], 1);
}

__global__ void k_scan1(const int* __restrict__ deg, int* __restrict__ ptr,
                        int* __restrict__ bsum, int n) {
    __shared__ int sd[256];
    int i = blockIdx.x * 256 + threadIdx.x;
    int v = (i < n) ? (deg[i] - 1) : 0;
    sd[threadIdx.x] = v;
    __syncthreads();
    for (int off = 1; off < 256; off <<= 1) {
        int t = (threadIdx.x >= off) ? sd[threadIdx.x - off] : 0;
        __syncthreads();
        sd[threadIdx.x] += t;
        __syncthreads();
    }
    if (i < n) ptr[i] = sd[threadIdx.x] - v;
    if (threadIdx.x == 255) bsum[blockIdx.x] = sd[255];
}

__global__ void k_scan2(int* __restrict__ bsum, int nb) {
    __shared__ int sd[512];
    int t = threadIdx.x;
    int v = (t < nb) ? bsum[t] : 0;
    sd[t] = v;
    __syncthreads();
    for (int off = 1; off < 512; off <<= 1) {
        int x = (t >= off) ? sd[t - off] : 0;
        __syncthreads();
        sd[t] += x;
        __syncthreads();
    }
    if (t < nb) bsum[t] = sd[t] - v;
}

// scan finalize + dis = deg^-0.5 (fused)
__global__ void k_scan3(int* __restrict__ ptr, const int* __restrict__ bsum,
                        const int* __restrict__ deg, float* __restrict__ dis, int n) {
    int i = blockIdx.x * 256 + threadIdx.x;
    if (i < n) {
        ptr[i] += bsum[blockIdx.x];
        dis[i] = rsqrtf((float)deg[i]);
    }
}

__global__ void k_fill(const int* __restrict__ row, const int* __restrict__ col,
                       const int* __restrict__ ptr, int* __restrict__ cursor,
                       int* __restrict__ csr_src, int e) {
    int i = blockIdx.x * blockDim.x + threadIdx.x;
    if (i < e) {
        int v = col[i];
        int s = atomicAdd(&cursor[v], 1);
        csr_src[ptr[v] + s] = row[i];
    }
}

__global__ void k_counts(const int* __restrict__ batch, float* __restrict__ counts,
                         int n, int B) {
    int g = blockIdx.x * blockDim.x + threadIdx.x;
    if (g >= B) return;
    auto lb = [&](int key) {
        int lo = 0, hi = n;
        while (lo < hi) { int mid = (lo + hi) >> 1; if (batch[mid] < key) lo = mid + 1; else hi = mid; }
        return lo;
    };
    counts[g] = (float)(lb(g + 1) - lb(g));
}

// AtomEncoder: wave per node, lane = 4 cols (float4 in, bf16x4 out); row-major out
__global__ __launch_bounds__(256) void k_atom(const int* __restrict__ x,
                                              const float* __restrict__ emb,
                                              short* __restrict__ h,
                                              int n, int F, int V) {
    int node = blockIdx.x * 4 + (threadIdx.x >> 6);
    int lane = threadIdx.x & 63;
    if (node >= n) return;
    int xv = x[node * F + (lane < F ? lane : 0)];
    float4 acc = {0.f, 0.f, 0.f, 0.f};
    for (int f = 0; f < F; ++f) {
        int idx = __shfl(xv, f, 64);
        const float4 v = *(const float4*)(emb + ((size_t)f * V + idx) * HDIM + lane * 4);
        acc.x += v.x; acc.y += v.y; acc.z += v.z; acc.w += v.w;
    }
    ushort4 o = { f2bf(acc.x), f2bf(acc.y), f2bf(acc.z), f2bf(acc.w) };
    *(ushort4*)(h + (size_t)node * HDIM + lane * 4) = o;
}

// transpose + convert all three W (fp32 [K][N]) -> Wt (bf16 [N][K]); grid.y = layer
__global__ void k_wt3(const float* __restrict__ W1, const float* __restrict__ W2,
                      const float* __restrict__ W3, short* __restrict__ Wt1,
                      short* __restrict__ Wt2, short* __restrict__ Wt3) {
    const float* W = (blockIdx.y == 0) ? W1 : (blockIdx.y == 1) ? W2 : W3;
    short* Wt      = (blockIdx.y == 0) ? Wt1 : (blockIdx.y == 1) ? Wt2 : Wt3;
    int i = blockIdx.x * 256 + threadIdx.x;
    int nn = i >> 8, k = i & 255;
    Wt[nn * HDIM + k] = (short)f2bf(W[k * HDIM + nn]);
}

// bf16 MFMA GEMM: C[n,256] = A[n,256] @ W, Wt = W^T bf16.
// One block = 128 rows x ALL 256 cols (A-tile fetched once); 4 waves, each
// wave 64x128 (acc[4][8]). Frag layouts per m89: A row=lane&15,k=(lane>>4)*8+i;
// D col=lane&15,row=(lane>>4)*4+reg.
__global__ __launch_bounds__(256) void k_gemm(const short* __restrict__ A,
                                              const short* __restrict__ Wt,
                                              short* __restrict__ Co, int n) {
    int wid  = threadIdx.x >> 6;
    int lane = threadIdx.x & 63;
    int wr = wid >> 1, wc = wid & 1;
    int row0 = blockIdx.x * 128 + wr * 64;
    int col0 = wc * 128;
    int lm = lane & 15;
    int kg = lane >> 4;
    f32x4 acc[4][8] = {};
    for (int kk = 0; kk < HDIM; kk += 32) {
        bf16x8 a[4], b[8];
#pragma unroll
        for (int i = 0; i < 4; ++i) {
            int r = row0 + i * 16 + lm;
            a[i] = (r < n) ? *(const bf16x8*)(A + (size_t)r * HDIM + kk + kg * 8)
                           : (bf16x8)(short)0;
        }
#pragma unroll
        for (int j = 0; j < 8; ++j) {
            int c = col0 + j * 16 + lm;
            b[j] = *(const bf16x8*)(Wt + (size_t)c * HDIM + kk + kg * 8);
        }
#pragma unroll
        for (int i = 0; i < 4; ++i)
#pragma unroll
            for (int j = 0; j < 8; ++j)
                acc[i][j] = __builtin_amdgcn_mfma_f32_16x16x32_bf16(a[i], b[j], acc[i][j], 0, 0, 0);
    }
#pragma unroll
    for (int i = 0; i < 4; ++i)
#pragma unroll
        for (int j = 0; j < 8; ++j) {
            int c = col0 + j * 16 + lm;
#pragma unroll
            for (int r4 = 0; r4 < 4; ++r4) {
                int r = row0 + i * 16 + kg * 4 + r4;
                if (r < n) Co[(size_t)r * HDIM + c] = (short)f2bf(acc[i][j][r4]);
            }
        }
}

// gather-aggregate: wave per node (R4 structure), supersteps of 8 edges with
// 4 independent row loads in flight per lane (MLP-deep pipeline).
// 32 lanes x ushort8 = one 512B message row; halves split even/odd edges;
// final xor-32 reduce merges them.
__global__ __launch_bounds__(256) void k_agg(const short* __restrict__ mS,
                                             const int* __restrict__ csr_src,
                                             const int* __restrict__ ptr,
                                             const int* __restrict__ deg,
                                             const float* __restrict__ dis,
                                             const float* __restrict__ bias,
                                             short* __restrict__ xout, int n) {
    int node = blockIdx.x * 4 + (threadIdx.x >> 6);
    if (node >= n) return;
    int lane = threadIdx.x & 63;
    int half = lane >> 5;
    int cl = lane & 31;                       // col group: 8 cols
    const unsigned short* m = (const unsigned short*)mS;
    float dv = dis[node];
    float acc[8] = {};
    if (half == 0) {                          // self-loop term
        u16x8 r = *(const u16x8*)(m + (size_t)node * HDIM + cl * 8);
        float sw = dv * dv;
#pragma unroll
        for (int j = 0; j < 8; ++j) acc[j] = sw * bf2f(r[j]);
    }
    int start = ptr[node];
    int cnt = deg[node] - 1;
    for (int base = 0; base < cnt; base += 64) {
        int mm = cnt - base; if (mm > 64) mm = 64;
        int uu = 0; float du = 0.f;
        if (lane < mm) {
            uu = __builtin_nontemporal_load(&csr_src[start + base + lane]);
            du = dis[uu];
        }
        int nst = (mm + 7) >> 3;              // supersteps of 8 edges (4/half)
        for (int s = 0; s < nst; ++s) {
            u16x8 r[4]; float w[4];
#pragma unroll
            for (int q = 0; q < 4; ++q) {     // issue 4 independent loads
                int i = 8 * s + 2 * q + half;
                int u   = __shfl(uu, i & 63, 64);
                float ww = dv * __shfl(du, i & 63, 64);
                bool v = i < mm;
                w[q] = v ? ww : 0.f;
                r[q] = *(const u16x8*)(m + (size_t)(v ? u : 0) * HDIM + cl * 8);
            }
#pragma unroll
            for (int q = 0; q < 4; ++q)
#pragma unroll
                for (int j = 0; j < 8; ++j) acc[j] += w[q] * bf2f(r[q][j]);
        }
    }
#pragma unroll
    for (int j = 0; j < 8; ++j) acc[j] += __shfl_xor(acc[j], 32, 64);
    if (half == 0) {
        const float4 b0 = *(const float4*)(bias + cl * 8);
        const float4 b1 = *(const float4*)(bias + cl * 8 + 4);
        float bb[8] = {b0.x, b0.y, b0.z, b0.w, b1.x, b1.y, b1.z, b1.w};
        u16x8 o;
#pragma unroll
        for (int j = 0; j < 8; ++j)
            o[j] = f2bf(fmaxf(acc[j] + bb[j], 0.f));
        *(u16x8*)((unsigned short*)xout + (size_t)node * HDIM + cl * 8) = o;
    }
}

// pooling: sum x1+x2+x3 rows per graph (sorted batch -> contiguous ranges)
__global__ __launch_bounds__(256) void k_pool(const short* __restrict__ x1,
                                              const short* __restrict__ x2,
                                              const short* __restrict__ x3,
                                              const int* __restrict__ batch,
                                              float* __restrict__ pooled, int n) {
    int g = blockIdx.x, seg = blockIdx.y, t = threadIdx.x;
    auto lb = [&](int key) {
        int lo = 0, hi = n;
        while (lo < hi) { int mid = (lo + hi) >> 1; if (batch[mid] < key) lo = mid + 1; else hi = mid; }
        return lo;
    };
    int lo = lb(g), hi = lb(g + 1);
    int len = hi - lo;
    int per = (len + (int)gridDim.y - 1) / (int)gridDim.y;
    int s0 = lo + seg * per;
    int s1 = s0 + per; if (s1 > hi) s1 = hi;
    float acc = 0.f;
    for (int r = s0; r < s1; ++r) {
        size_t base = (size_t)r * HDIM + t;
        acc += bf2f((unsigned short)x1[base]) + bf2f((unsigned short)x2[base])
             + bf2f((unsigned short)x3[base]);
    }
    if (s0 < s1) atomicAdd(&pooled[g * HDIM + t], acc);
}

// classifier: mean-pool finalize + 2-layer MLP; block per graph
__global__ __launch_bounds__(H2) void k_cls(const float* __restrict__ pooled,
                                            const float* __restrict__ counts,
                                            const float* __restrict__ cw1,
                                            const float* __restrict__ cb1,
                                            const float* __restrict__ cw2,
                                            const float* __restrict__ cb2,
                                            float* __restrict__ out, int B, int C) {
    __shared__ float sp[HDIM];
    __shared__ float sh[H2];
    int g = blockIdx.x, t = threadIdx.x;
    float inv = 1.0f / counts[g];
    sp[t] = pooled[g * HDIM + t] * inv;
    sp[t + H2] = pooled[g * HDIM + t + H2] * inv;
    __syncthreads();
    float acc = cb1[t];
    for (int h = 0; h < HDIM; ++h) acc += sp[h] * cw1[h * H2 + t];
    sh[t] = fmaxf(acc, 0.f);
    __syncthreads();
    if (t < C) {
        float o = cb2[t];
        for (int j = 0; j < H2; ++j) o += sh[j] * cw2[j * C + t];
        out[g * C + t] = o;
    }
    if (g == 0 && t == 0) out[B * C] = 0.f;
}

// ---------------------------------------------------------------------------
extern "C" void kernel_launch(void* const* d_in, const int* in_sizes, int n_in,
                              void* d_out, int out_size, void* d_ws, size_t ws_size,
                              hipStream_t stream) {
    const int* x      = (const int*)d_in[0];
    const int* erow   = (const int*)d_in[1];
    const int* batch  = (const int*)d_in[2];
    const float* emb  = (const float*)d_in[3];
    const float* W1   = (const float*)d_in[4];
    const float* b1   = (const float*)d_in[5];
    const float* W2   = (const float*)d_in[6];
    const float* b2   = (const float*)d_in[7];
    const float* W3   = (const float*)d_in[8];
    const float* b3   = (const float*)d_in[9];
    const float* cw1  = (const float*)d_in[10];
    const float* cb1  = (const float*)d_in[11];
    const float* cw2  = (const float*)d_in[12];
    const float* cb2  = (const float*)d_in[13];
    float* out = (float*)d_out;

    const int N = in_sizes[2];
    const int E = in_sizes[1] / 2;
    const int F = in_sizes[0] / N;
    const int V = in_sizes[3] / (F * HDIM);
    const int C = in_sizes[13];
    const int B = (out_size - 1) / C;
    const int* ecol = erow + E;

    char* w = (char*)d_ws;
    auto carve = [&](size_t bytes) {
        void* p = (void*)w;
        w += (bytes + 255) & ~(size_t)255;
        return p;
    };
    short* P0     = (short*)carve((size_t)N * HDIM * 2);   // h0, later x3
    short* P1     = (short*)carve((size_t)N * HDIM * 2);   // x1
    short* P2     = (short*)carve((size_t)N * HDIM * 2);   // x2
    short* mS     = (short*)carve((size_t)N * HDIM * 2);   // GEMM output (messages)
    short* Wt1    = (short*)carve((size_t)HDIM * HDIM * 2);
    short* Wt2    = (short*)carve((size_t)HDIM * HDIM * 2);
    short* Wt3    = (short*)carve((size_t)HDIM * HDIM * 2);
    float* dis    = (float*)carve((size_t)N * 4);
    float* pooled = (float*)carve((size_t)B * HDIM * 4);
    float* counts = (float*)carve((size_t)B * 4);
    int* deg      = (int*)carve((size_t)N * 4);
    int* ptr      = (int*)carve((size_t)N * 4);
    int* cursor   = (int*)carve((size_t)N * 4);
    int* bsum     = (int*)carve(1024 * 4);
    int* csr      = (int*)carve((size_t)E * 4);

    int nblk = (N + 255) / 256;
    int initspan = (B * HDIM > N) ? B * HDIM : N;

    k_init<<<(initspan + 255) / 256, 256, 0, stream>>>(deg, cursor, pooled, N, B * HDIM);
    k_deg<<<(E + 255) / 256, 256, 0, stream>>>(ecol, deg, E);
    k_scan1<<<nblk, 256, 0, stream>>>(deg, ptr, bsum, N);
    k_scan2<<<1, 512, 0, stream>>>(bsum, nblk);
    k_scan3<<<nblk, 256, 0, stream>>>(ptr, bsum, deg, dis, N);
    k_fill<<<(E + 255) / 256, 256, 0, stream>>>(erow, ecol, ptr, cursor, csr, E);
    k_counts<<<(B + 255) / 256, 256, 0, stream>>>(batch, counts, N, B);
    dim3 wgrid(HDIM, 3);
    k_wt3<<<wgrid, 256, 0, stream>>>(W1, W2, W3, Wt1, Wt2, Wt3);
    k_atom<<<(N + 3) / 4, 256, 0, stream>>>(x, emb, P0, N, F, V);

    int ggrid = (N + 127) / 128;
    int agrid = (N + 3) / 4;

    k_gemm<<<ggrid, 256, 0, stream>>>(P0, Wt1, mS, N);
    k_agg<<<agrid, 256, 0, stream>>>(mS, csr, ptr, deg, dis, b1, P1, N);
    k_gemm<<<ggrid, 256, 0, stream>>>(P1, Wt2, mS, N);
    k_agg<<<agrid, 256, 0, stream>>>(mS, csr, ptr, deg, dis, b2, P2, N);
    k_gemm<<<ggrid, 256, 0, stream>>>(P2, Wt3, mS, N);
    k_agg<<<agrid, 256, 0, stream>>>(mS, csr, ptr, deg, dis, b3, P0, N);

    dim3 pgrid(B, 4);
    k_pool<<<pgrid, 256, 0, stream>>>(P1, P2, P0, batch, pooled, N);
    k_cls<<<B, H2, 0, stream>>>(pooled, counts, cw1, cb1, cw2, cb2, out, B, C);
}

// Round 8
// 780.620 us; speedup vs baseline: 2.0984x; 1.0726x over previous
//
#include <hip/hip_runtime.h>
#include <hip/hip_bf16.h>
#include <cstdint>

#define HDIM 256
#define H2   128

using f32x4  = __attribute__((ext_vector_type(4))) float;
using bf16x8 = __attribute__((ext_vector_type(8))) short;    // 8 bf16 in 4 VGPRs
using u16x8  = __attribute__((ext_vector_type(8))) unsigned short;

__device__ inline unsigned short f2bf(float f) {             // round-to-nearest-even
    unsigned x = __builtin_bit_cast(unsigned, f);
    return (unsigned short)((x + 0x7fffu + ((x >> 16) & 1u)) >> 16);
}
__device__ inline float bf2f(unsigned short u) {
    unsigned x = ((unsigned)u) << 16;
    return __builtin_bit_cast(float, x);
}

// ---------------------------------------------------------------------------
__global__ void k_init(int* __restrict__ deg, int* __restrict__ cursor,
                       float* __restrict__ pooled, int n, int bh) {
    int i = blockIdx.x * blockDim.x + threadIdx.x;
    if (i < n) { deg[i] = 1; cursor[i] = 0; }
    if (i < bh) pooled[i] = 0.f;
}

__global__ void k_deg(const int* __restrict__ col, int* __restrict__ deg, int e) {
    int i = blockIdx.x * blockDim.x + threadIdx.x;
    if (i < e) atomicAdd(&deg[col[i]], 1);
}

__global__ void k_scan1(const int* __restrict__ deg, int* __restrict__ ptr,
                        int* __restrict__ bsum, int n) {
    __shared__ int sd[256];
    int i = blockIdx.x * 256 + threadIdx.x;
    int v = (i < n) ? (deg[i] - 1) : 0;
    sd[threadIdx.x] = v;
    __syncthreads();
    for (int off = 1; off < 256; off <<= 1) {
        int t = (threadIdx.x >= off) ? sd[threadIdx.x - off] : 0;
        __syncthreads();
        sd[threadIdx.x] += t;
        __syncthreads();
    }
    if (i < n) ptr[i] = sd[threadIdx.x] - v;
    if (threadIdx.x == 255) bsum[blockIdx.x] = sd[255];
}

__global__ void k_scan2(int* __restrict__ bsum, int nb) {
    __shared__ int sd[512];
    int t = threadIdx.x;
    int v = (t < nb) ? bsum[t] : 0;
    sd[t] = v;
    __syncthreads();
    for (int off = 1; off < 512; off <<= 1) {
        int x = (t >= off) ? sd[t - off] : 0;
        __syncthreads();
        sd[t] += x;
        __syncthreads();
    }
    if (t < nb) bsum[t] = sd[t] - v;
}

// scan finalize + dis = deg^-0.5 (fused)
__global__ void k_scan3(int* __restrict__ ptr, const int* __restrict__ bsum,
                        const int* __restrict__ deg, float* __restrict__ dis, int n) {
    int i = blockIdx.x * 256 + threadIdx.x;
    if (i < n) {
        ptr[i] += bsum[blockIdx.x];
        dis[i] = rsqrtf((float)deg[i]);
    }
}

__global__ void k_fill(const int* __restrict__ row, const int* __restrict__ col,
                       const int* __restrict__ ptr, int* __restrict__ cursor,
                       int* __restrict__ csr_src, int e) {
    int i = blockIdx.x * blockDim.x + threadIdx.x;
    if (i < e) {
        int v = col[i];
        int s = atomicAdd(&cursor[v], 1);
        csr_src[ptr[v] + s] = row[i];
    }
}

__global__ void k_counts(const int* __restrict__ batch, float* __restrict__ counts,
                         int n, int B) {
    int g = blockIdx.x * blockDim.x + threadIdx.x;
    if (g >= B) return;
    auto lb = [&](int key) {
        int lo = 0, hi = n;
        while (lo < hi) { int mid = (lo + hi) >> 1; if (batch[mid] < key) lo = mid + 1; else hi = mid; }
        return lo;
    };
    counts[g] = (float)(lb(g + 1) - lb(g));
}

// AtomEncoder: wave per node, lane = 4 cols (float4 in, bf16x4 out); row-major out
__global__ __launch_bounds__(256) void k_atom(const int* __restrict__ x,
                                              const float* __restrict__ emb,
                                              short* __restrict__ h,
                                              int n, int F, int V) {
    int node = blockIdx.x * 4 + (threadIdx.x >> 6);
    int lane = threadIdx.x & 63;
    if (node >= n) return;
    int xv = x[node * F + (lane < F ? lane : 0)];
    float4 acc = {0.f, 0.f, 0.f, 0.f};
    for (int f = 0; f < F; ++f) {
        int idx = __shfl(xv, f, 64);
        const float4 v = *(const float4*)(emb + ((size_t)f * V + idx) * HDIM + lane * 4);
        acc.x += v.x; acc.y += v.y; acc.z += v.z; acc.w += v.w;
    }
    ushort4 o = { f2bf(acc.x), f2bf(acc.y), f2bf(acc.z), f2bf(acc.w) };
    *(ushort4*)(h + (size_t)node * HDIM + lane * 4) = o;
}

// transpose + convert all three W (fp32 [K][N]) -> Wt (bf16 [N][K]); grid.y = layer
__global__ void k_wt3(const float* __restrict__ W1, const float* __restrict__ W2,
                      const float* __restrict__ W3, short* __restrict__ Wt1,
                      short* __restrict__ Wt2, short* __restrict__ Wt3) {
    const float* W = (blockIdx.y == 0) ? W1 : (blockIdx.y == 1) ? W2 : W3;
    short* Wt      = (blockIdx.y == 0) ? Wt1 : (blockIdx.y == 1) ? Wt2 : Wt3;
    int i = blockIdx.x * 256 + threadIdx.x;
    int nn = i >> 8, k = i & 255;
    Wt[nn * HDIM + k] = (short)f2bf(W[k * HDIM + nn]);
}

// bf16 MFMA GEMM: C[n,256] = A[n,256] @ W, Wt = W^T bf16.
// Block = 512 threads = 8 waves (2 row-waves x 4 col-waves of 64x64).
// A-tile (128 rows x 256 k, 64 KB) staged ONCE in LDS, XOR-swizzled
// (byte ^= (row&7)<<4) to kill the 512B-row-stride bank conflict (G4).
// B-frags direct from L2-hot Wt. acc[4][4]=64 VGPR -> 4 waves/SIMD.
__global__ __launch_bounds__(512, 4) void k_gemm(const short* __restrict__ A,
                                                 const short* __restrict__ Wt,
                                                 short* __restrict__ Co, int n) {
    __shared__ unsigned char As[128 * 512];    // 64 KB
    int row0 = blockIdx.x * 128;
    int t = threadIdx.x;
    const unsigned short* A16 = (const unsigned short*)A;
    // stage A-tile: 4096 chunks of 16B, 8 per thread; swizzled ds_write
#pragma unroll
    for (int j = 0; j < 8; ++j) {
        int c = j * 512 + t;
        int r = c >> 5;                         // tile row 0..127
        int wb = (c & 31) * 16;                 // byte within row
        int gr = row0 + r; if (gr >= n) gr = n - 1;
        u16x8 v = *(const u16x8*)(A16 + (size_t)gr * HDIM + (wb >> 1));
        *(u16x8*)(As + r * 512 + (wb ^ ((r & 7) << 4))) = v;
    }
    __syncthreads();

    int wid  = t >> 6;
    int lane = t & 63;
    int wr = wid >> 2, wc = wid & 3;
    int lm = lane & 15;
    int kg = lane >> 4;
    int colw = wc * 64;
    f32x4 acc[4][4] = {};
#pragma unroll 2
    for (int kk = 0; kk < 8; ++kk) {            // k-chunk of 32 elems (64 B)
        bf16x8 a[4], b[4];
#pragma unroll
        for (int i = 0; i < 4; ++i) {
            int R = wr * 64 + i * 16 + lm;
            int boff = (kk * 64 + kg * 16) ^ ((R & 7) << 4);
            a[i] = *(const bf16x8*)(As + R * 512 + boff);
        }
#pragma unroll
        for (int j = 0; j < 4; ++j) {
            int cidx = colw + j * 16 + lm;
            b[j] = *(const bf16x8*)(Wt + (size_t)cidx * HDIM + kk * 32 + kg * 8);
        }
#pragma unroll
        for (int i = 0; i < 4; ++i)
#pragma unroll
            for (int j = 0; j < 4; ++j)
                acc[i][j] = __builtin_amdgcn_mfma_f32_16x16x32_bf16(a[i], b[j], acc[i][j], 0, 0, 0);
    }
#pragma unroll
    for (int i = 0; i < 4; ++i)
#pragma unroll
        for (int j = 0; j < 4; ++j) {
            int c = colw + j * 16 + lm;
#pragma unroll
            for (int r4 = 0; r4 < 4; ++r4) {
                int r = row0 + wr * 64 + i * 16 + kg * 4 + r4;
                if (r < n) Co[(size_t)r * HDIM + c] = (short)f2bf(acc[i][j][r4]);
            }
        }
}

// gather-aggregate: wave per node, supersteps of 8 edges with 4 independent
// row loads in flight per lane. 32 lanes x ushort8 = one 512B message row;
// halves split even/odd edges; final xor-32 reduce merges them.
__global__ __launch_bounds__(256) void k_agg(const short* __restrict__ mS,
                                             const int* __restrict__ csr_src,
                                             const int* __restrict__ ptr,
                                             const int* __restrict__ deg,
                                             const float* __restrict__ dis,
                                             const float* __restrict__ bias,
                                             short* __restrict__ xout, int n) {
    int node = blockIdx.x * 4 + (threadIdx.x >> 6);
    if (node >= n) return;
    int lane = threadIdx.x & 63;
    int half = lane >> 5;
    int cl = lane & 31;                       // col group: 8 cols
    const unsigned short* m = (const unsigned short*)mS;
    float dv = dis[node];
    float acc[8] = {};
    if (half == 0) {                          // self-loop term
        u16x8 r = *(const u16x8*)(m + (size_t)node * HDIM + cl * 8);
        float sw = dv * dv;
#pragma unroll
        for (int j = 0; j < 8; ++j) acc[j] = sw * bf2f(r[j]);
    }
    int start = ptr[node];
    int cnt = deg[node] - 1;
    for (int base = 0; base < cnt; base += 64) {
        int mm = cnt - base; if (mm > 64) mm = 64;
        int uu = 0; float du = 0.f;
        if (lane < mm) {
            uu = __builtin_nontemporal_load(&csr_src[start + base + lane]);
            du = dis[uu];
        }
        int nst = (mm + 7) >> 3;              // supersteps of 8 edges (4/half)
        for (int s = 0; s < nst; ++s) {
            u16x8 r[4]; float w[4];
#pragma unroll
            for (int q = 0; q < 4; ++q) {     // issue 4 independent loads
                int i = 8 * s + 2 * q + half;
                int u   = __shfl(uu, i & 63, 64);
                float ww = dv * __shfl(du, i & 63, 64);
                bool v = i < mm;
                w[q] = v ? ww : 0.f;
                r[q] = *(const u16x8*)(m + (size_t)(v ? u : 0) * HDIM + cl * 8);
            }
#pragma unroll
            for (int q = 0; q < 4; ++q)
#pragma unroll
                for (int j = 0; j < 8; ++j) acc[j] += w[q] * bf2f(r[q][j]);
        }
    }
#pragma unroll
    for (int j = 0; j < 8; ++j) acc[j] += __shfl_xor(acc[j], 32, 64);
    if (half == 0) {
        const float4 b0 = *(const float4*)(bias + cl * 8);
        const float4 b1 = *(const float4*)(bias + cl * 8 + 4);
        float bb[8] = {b0.x, b0.y, b0.z, b0.w, b1.x, b1.y, b1.z, b1.w};
        u16x8 o;
#pragma unroll
        for (int j = 0; j < 8; ++j)
            o[j] = f2bf(fmaxf(acc[j] + bb[j], 0.f));
        *(u16x8*)((unsigned short*)xout + (size_t)node * HDIM + cl * 8) = o;
    }
}

// pooling: sum x1+x2+x3 rows per graph (sorted batch -> contiguous ranges)
__global__ __launch_bounds__(256) void k_pool(const short* __restrict__ x1,
                                              const short* __restrict__ x2,
                                              const short* __restrict__ x3,
                                              const int* __restrict__ batch,
                                              float* __restrict__ pooled, int n) {
    int g = blockIdx.x, seg = blockIdx.y, t = threadIdx.x;
    auto lb = [&](int key) {
        int lo = 0, hi = n;
        while (lo < hi) { int mid = (lo + hi) >> 1; if (batch[mid] < key) lo = mid + 1; else hi = mid; }
        return lo;
    };
    int lo = lb(g), hi = lb(g + 1);
    int len = hi - lo;
    int per = (len + (int)gridDim.y - 1) / (int)gridDim.y;
    int s0 = lo + seg * per;
    int s1 = s0 + per; if (s1 > hi) s1 = hi;
    float acc = 0.f;
    for (int r = s0; r < s1; ++r) {
        size_t base = (size_t)r * HDIM + t;
        acc += bf2f((unsigned short)x1[base]) + bf2f((unsigned short)x2[base])
             + bf2f((unsigned short)x3[base]);
    }
    if (s0 < s1) atomicAdd(&pooled[g * HDIM + t], acc);
}

// classifier: mean-pool finalize + 2-layer MLP; block per graph
__global__ __launch_bounds__(H2) void k_cls(const float* __restrict__ pooled,
                                            const float* __restrict__ counts,
                                            const float* __restrict__ cw1,
                                            const float* __restrict__ cb1,
                                            const float* __restrict__ cw2,
                                            const float* __restrict__ cb2,
                                            float* __restrict__ out, int B, int C) {
    __shared__ float sp[HDIM];
    __shared__ float sh[H2];
    int g = blockIdx.x, t = threadIdx.x;
    float inv = 1.0f / counts[g];
    sp[t] = pooled[g * HDIM + t] * inv;
    sp[t + H2] = pooled[g * HDIM + t + H2] * inv;
    __syncthreads();
    float acc = cb1[t];
    for (int h = 0; h < HDIM; ++h) acc += sp[h] * cw1[h * H2 + t];
    sh[t] = fmaxf(acc, 0.f);
    __syncthreads();
    if (t < C) {
        float o = cb2[t];
        for (int j = 0; j < H2; ++j) o += sh[j] * cw2[j * C + t];
        out[g * C + t] = o;
    }
    if (g == 0 && t == 0) out[B * C] = 0.f;
}

// ---------------------------------------------------------------------------
extern "C" void kernel_launch(void* const* d_in, const int* in_sizes, int n_in,
                              void* d_out, int out_size, void* d_ws, size_t ws_size,
                              hipStream_t stream) {
    const int* x      = (const int*)d_in[0];
    const int* erow   = (const int*)d_in[1];
    const int* batch  = (const int*)d_in[2];
    const float* emb  = (const float*)d_in[3];
    const float* W1   = (const float*)d_in[4];
    const float* b1   = (const float*)d_in[5];
    const float* W2   = (const float*)d_in[6];
    const float* b2   = (const float*)d_in[7];
    const float* W3   = (const float*)d_in[8];
    const float* b3   = (const float*)d_in[9];
    const float* cw1  = (const float*)d_in[10];
    const float* cb1  = (const float*)d_in[11];
    const float* cw2  = (const float*)d_in[12];
    const float* cb2  = (const float*)d_in[13];
    float* out = (float*)d_out;

    const int N = in_sizes[2];
    const int E = in_sizes[1] / 2;
    const int F = in_sizes[0] / N;
    const int V = in_sizes[3] / (F * HDIM);
    const int C = in_sizes[13];
    const int B = (out_size - 1) / C;
    const int* ecol = erow + E;

    char* w = (char*)d_ws;
    auto carve = [&](size_t bytes) {
        void* p = (void*)w;
        w += (bytes + 255) & ~(size_t)255;
        return p;
    };
    short* P0     = (short*)carve((size_t)N * HDIM * 2);   // h0, later x3
    short* P1     = (short*)carve((size_t)N * HDIM * 2);   // x1
    short* P2     = (short*)carve((size_t)N * HDIM * 2);   // x2
    short* mS     = (short*)carve((size_t)N * HDIM * 2);   // GEMM output (messages)
    short* Wt1    = (short*)carve((size_t)HDIM * HDIM * 2);
    short* Wt2    = (short*)carve((size_t)HDIM * HDIM * 2);
    short* Wt3    = (short*)carve((size_t)HDIM * HDIM * 2);
    float* dis    = (float*)carve((size_t)N * 4);
    float* pooled = (float*)carve((size_t)B * HDIM * 4);
    float* counts = (float*)carve((size_t)B * 4);
    int* deg      = (int*)carve((size_t)N * 4);
    int* ptr      = (int*)carve((size_t)N * 4);
    int* cursor   = (int*)carve((size_t)N * 4);
    int* bsum     = (int*)carve(1024 * 4);
    int* csr      = (int*)carve((size_t)E * 4);

    int nblk = (N + 255) / 256;
    int initspan = (B * HDIM > N) ? B * HDIM : N;

    k_init<<<(initspan + 255) / 256, 256, 0, stream>>>(deg, cursor, pooled, N, B * HDIM);
    k_deg<<<(E + 255) / 256, 256, 0, stream>>>(ecol, deg, E);
    k_scan1<<<nblk, 256, 0, stream>>>(deg, ptr, bsum, N);
    k_scan2<<<1, 512, 0, stream>>>(bsum, nblk);
    k_scan3<<<nblk, 256, 0, stream>>>(ptr, bsum, deg, dis, N);
    k_fill<<<(E + 255) / 256, 256, 0, stream>>>(erow, ecol, ptr, cursor, csr, E);
    k_counts<<<(B + 255) / 256, 256, 0, stream>>>(batch, counts, N, B);
    dim3 wgrid(HDIM, 3);
    k_wt3<<<wgrid, 256, 0, stream>>>(W1, W2, W3, Wt1, Wt2, Wt3);
    k_atom<<<(N + 3) / 4, 256, 0, stream>>>(x, emb, P0, N, F, V);

    int ggrid = (N + 127) / 128;
    int agrid = (N + 3) / 4;

    k_gemm<<<ggrid, 512, 0, stream>>>(P0, Wt1, mS, N);
    k_agg<<<agrid, 256, 0, stream>>>(mS, csr, ptr, deg, dis, b1, P1, N);
    k_gemm<<<ggrid, 512, 0, stream>>>(P1, Wt2, mS, N);
    k_agg<<<agrid, 256, 0, stream>>>(mS, csr, ptr, deg, dis, b2, P2, N);
    k_gemm<<<ggrid, 512, 0, stream>>>(P2, Wt3, mS, N);
    k_agg<<<agrid, 256, 0, stream>>>(mS, csr, ptr, deg, dis, b3, P0, N);

    dim3 pgrid(B, 4);
    k_pool<<<pgrid, 256, 0, stream>>>(P1, P2, P0, batch, pooled, N);
    k_cls<<<B, H2, 0, stream>>>(pooled, counts, cw1, cb1, cw2, cb2, out, B, C);
}